// Round 9
// baseline (479.556 us; speedup 1.0000x reference)
//
#include <hip/hip_runtime.h>

#define BATCH 16
#define CH    64
#define TLEN  200
#define NP    30
#define HID   128
#define G4    512            // 4*HID
#define NSEQ  (BATCH * NP)   // 480
#define HROW  132            // hbuf row stride in halves: 264 B -> conflict-free (R7-verified)

typedef _Float16 f16x4 __attribute__((ext_vector_type(4)));
typedef _Float16 half8 __attribute__((ext_vector_type(8)));
typedef float    f32x4 __attribute__((ext_vector_type(4)));

__device__ __forceinline__ float sigm_fast(float x) {
    return __builtin_amdgcn_rcpf(1.0f + __expf(-x));
}
__device__ __forceinline__ float tanh_fast(float x) {
    float xc = fminf(15.0f, fmaxf(-15.0f, x));
    float e = __expf(2.0f * xc);
    return (e - 1.0f) * __builtin_amdgcn_rcpf(e + 1.0f);
}

// LDS-only barrier (R8). Keeps compiler from reordering LDS ops across it;
// global loads pinned on the issue side of it by the memory clobber.
__device__ __forceinline__ void barrier_lds_only() {
    asm volatile("s_waitcnt lgkmcnt(0)\n\ts_barrier" ::: "memory");
}

__device__ __forceinline__ float4 load4(const float* p) {
    return *(const float4*)p;
}
__device__ __forceinline__ float4 load4(const _Float16* p) {
    f16x4 v = *(const f16x4*)p;
    return make_float4((float)v[0], (float)v[1], (float)v[2], (float)v[3]);
}

// ---------------------------------------------------------------------------
// Phase 1 (unchanged from R7/R8): xg[n][t][g] = dot(x[b,:,t,p], W_ih[g,:]) + bias
// ---------------------------------------------------------------------------
template <typename XT>
__global__ __launch_bounds__(512) void xg_kernel(
    const float* __restrict__ x, const float* __restrict__ W_ih,
    const float* __restrict__ b_ih, const float* __restrict__ b_hh,
    XT* __restrict__ xg)
{
    const int t0  = blockIdx.x * 2;
    const int b   = blockIdx.y;
    const int tid = threadIdx.x;

    __shared__ float ws[CH][G4 + 1];
    __shared__ float xs[CH][64];

    {
        const float4* W4 = (const float4*)W_ih;
#pragma unroll
        for (int i = 0; i < 16; ++i) {
            float4 v = W4[i * 512 + tid];
            int base = 4 * (i * 512 + tid);
            int g = base >> 6;
            int k = base & 63;
            ws[k][g] = v.x; ws[k + 1][g] = v.y; ws[k + 2][g] = v.z; ws[k + 3][g] = v.w;
        }
    }
    {
        const int c = tid >> 3, sub = tid & 7;
#pragma unroll
        for (int tt = 0; tt < 2; ++tt) {
            const float* xr = x + ((size_t)(b * CH + c) * TLEN + (t0 + tt)) * NP;
            for (int p = sub; p < NP; p += 8) xs[c][tt * 32 + p] = xr[p];
        }
    }

    const int gq   = tid & 63;
    const int posq = tid >> 6;
    const int pos0 = posq * 8;

    float bias[8];
#pragma unroll
    for (int j = 0; j < 8; ++j) {
        int g = gq + 64 * j;
        bias[j] = b_ih[g] + b_hh[g];
    }
    __syncthreads();

    float acc[8][8];
#pragma unroll
    for (int j = 0; j < 8; ++j)
#pragma unroll
        for (int i = 0; i < 8; ++i) acc[j][i] = 0.f;

#pragma unroll 4
    for (int k = 0; k < CH; ++k) {
        float w[8];
#pragma unroll
        for (int j = 0; j < 8; ++j) w[j] = ws[k][gq + 64 * j];
        float4 xlo = *(const float4*)&xs[k][pos0];
        float4 xhi = *(const float4*)&xs[k][pos0 + 4];
        float xv[8] = {xlo.x, xlo.y, xlo.z, xlo.w, xhi.x, xhi.y, xhi.z, xhi.w};
#pragma unroll
        for (int j = 0; j < 8; ++j)
#pragma unroll
            for (int i = 0; i < 8; ++i) acc[j][i] = fmaf(w[j], xv[i], acc[j][i]);
    }

#pragma unroll
    for (int i = 0; i < 8; ++i) {
        int pos = pos0 + i;
        int tt = pos >> 5, p = pos & 31;
        if (p >= NP) continue;
        int n = b * NP + p;
        size_t rowbase = ((size_t)n * TLEN + (t0 + tt)) * G4;
#pragma unroll
        for (int j = 0; j < 8; ++j) {
            int g = gq + 64 * j;
            xg[rowbase + g] = (XT)(acc[j][i] + bias[j]);
        }
    }
}

// ---------------------------------------------------------------------------
// Phase 2: MFMA LSTM, operand roles SWAPPED vs R6-R8.
//   A = W_hh slice (resident 64 VGPRs): A[m=gate][k=hid], lane m=l15, k=quad*8+j
//   B = h from LDS:                     B[k=hid][n=seq],  lane n=l15, k=quad*8+j
//   D[m=gate quad*4+r][n=seq l15]
// => lane's xg need = CONTIGUOUS float4 per gate-type q: 4 coalesced
//    dwordx4 loads/step (R6-R8: 16 scattered scalar loads that the allocator
//    kept sinking to use, exposing full memory latency every step).
// h write = single b64 (4 contiguous halves). h read identical conflict-free
// b128 pattern as before.
// ---------------------------------------------------------------------------
template <typename XT>
__global__ __attribute__((amdgpu_flat_work_group_size(512, 512)))
__attribute__((amdgpu_waves_per_eu(2, 2)))
void lstm_kernel(
    const XT* __restrict__ xg, const float* __restrict__ W_hh,
    const float* __restrict__ W_fc, const float* __restrict__ b_fc,
    float* __restrict__ out)
{
    const int blk = blockIdx.x;       // 0..29
    const int n0  = blk * 16;
    const int tid = threadIdx.x;
    const int w   = tid >> 6;         // wave 0..7
    const int l   = tid & 63;
    const int l15 = l & 15;           // seq index (D col / B col / A row)
    const int quad = l >> 4;

    __shared__ _Float16 hbuf[2][16][HROW];   // [buf][seq][hid]

    {
        _Float16* hz = &hbuf[0][0][0];
        for (int i = tid; i < 2 * 16 * HROW; i += 512) hz[i] = (_Float16)0;
    }

    // A-frags: W_hh resident. afrag[q][kt][j] = W_hh[q*128 + w*16 + l15][kt*32 + quad*8 + j]
    half8 afrag[4][4];
#pragma unroll
    for (int q = 0; q < 4; ++q) {
        const float* wrow = W_hh + (size_t)(q * 128 + w * 16 + l15) * HID;
#pragma unroll
        for (int kt = 0; kt < 4; ++kt) {
            const float4* p = (const float4*)(wrow + kt * 32 + quad * 8);
            float4 f0 = p[0], f1 = p[1];
            afrag[q][kt] = (half8){(_Float16)f0.x, (_Float16)f0.y, (_Float16)f0.z, (_Float16)f0.w,
                                   (_Float16)f1.x, (_Float16)f1.y, (_Float16)f1.z, (_Float16)f1.w};
        }
    }

    // xg per-lane base: seq = n0 + l15, gates [w*16 + quad*4 .. +4) per q
    const XT* pxg = xg + (size_t)(n0 + l15) * TLEN * G4 + (w * 16 + quad * 4);

    float4 cur[4], nxt[4];
#pragma unroll
    for (int q = 0; q < 4; ++q) cur[q] = load4(pxg + q * 128);   // t = 0

    float cst[4] = {0.f, 0.f, 0.f, 0.f};   // c-state: seq l15, hid w*16+quad*4+r
    __syncthreads();

    for (int t = 0; t < TLEN; ++t) {
        // issue next step's xg loads FIRST (coalesced dwordx4; live 1 step)
        const size_t toff = (size_t)(t + 1 < TLEN ? t + 1 : t) * G4;
#pragma unroll
        for (int q = 0; q < 4; ++q) nxt[q] = load4(pxg + toff + q * 128);

        // B-frags: h[seq l15][kt*32 + quad*8 ..+8] (conflict-free b128)
        const _Float16* hrd = &hbuf[t & 1][0][0];
        half8 bf[4];
#pragma unroll
        for (int kt = 0; kt < 4; ++kt)
            bf[kt] = *(const half8*)(hrd + l15 * HROW + kt * 32 + quad * 8);

        f32x4 acc0 = {0.f, 0.f, 0.f, 0.f};
        f32x4 acc1 = {0.f, 0.f, 0.f, 0.f};
        f32x4 acc2 = {0.f, 0.f, 0.f, 0.f};
        f32x4 acc3 = {0.f, 0.f, 0.f, 0.f};
#pragma unroll
        for (int kt = 0; kt < 4; ++kt) {
            acc0 = __builtin_amdgcn_mfma_f32_16x16x32_f16(afrag[0][kt], bf[kt], acc0, 0, 0, 0);
            acc1 = __builtin_amdgcn_mfma_f32_16x16x32_f16(afrag[1][kt], bf[kt], acc1, 0, 0, 0);
            acc2 = __builtin_amdgcn_mfma_f32_16x16x32_f16(afrag[2][kt], bf[kt], acc2, 0, 0, 0);
            acc3 = __builtin_amdgcn_mfma_f32_16x16x32_f16(afrag[3][kt], bf[kt], acc3, 0, 0, 0);
        }

        // update: lane owns (seq l15, hid w*16+quad*4+r); xg added here (max cover)
        f16x4 hv;
#pragma unroll
        for (int r = 0; r < 4; ++r) {
            float ii = sigm_fast(acc0[r] + ((const float*)&cur[0])[r]);
            float ff = sigm_fast(acc1[r] + ((const float*)&cur[1])[r]);
            float gg = tanh_fast(acc2[r] + ((const float*)&cur[2])[r]);
            float oo = sigm_fast(acc3[r] + ((const float*)&cur[3])[r]);
            float cn = ff * cst[r] + ii * gg;
            cst[r] = cn;
            hv[r] = (_Float16)(oo * tanh_fast(cn));
        }
        *(f16x4*)&hbuf[(t + 1) & 1][l15][w * 16 + quad * 4] = hv;

#pragma unroll
        for (int q = 0; q < 4; ++q) cur[q] = nxt[q];
        barrier_lds_only();
    }

    // FC epilogue: final h (t=200 even) in hbuf[0], rows = seq
    for (int i = tid; i < 16 * CH; i += 512) {
        const int s = i >> 6, ch = i & 63;
        const float4* wf = (const float4*)(W_fc + (size_t)ch * HID);
        const _Float16* hrow = &hbuf[0][s][0];
        float a = b_fc[ch];
#pragma unroll
        for (int j = 0; j < 32; ++j) {
            float4 w4 = wf[j];
            a += w4.x * (float)hrow[4 * j]     + w4.y * (float)hrow[4 * j + 1]
               + w4.z * (float)hrow[4 * j + 2] + w4.w * (float)hrow[4 * j + 3];
        }
        out[(size_t)(n0 + s) * CH + ch] = a;
    }
}

extern "C" void kernel_launch(void* const* d_in, const int* in_sizes, int n_in,
                              void* d_out, int out_size, void* d_ws, size_t ws_size,
                              hipStream_t stream) {
    (void)in_sizes; (void)n_in; (void)out_size;
    const float* x    = (const float*)d_in[0];
    const float* W_ih = (const float*)d_in[1];
    const float* W_hh = (const float*)d_in[2];
    const float* b_ih = (const float*)d_in[3];
    const float* b_hh = (const float*)d_in[4];
    const float* W_fc = (const float*)d_in[5];
    const float* b_fc = (const float*)d_in[6];
    float* out = (float*)d_out;

    const size_t need_f32 = (size_t)NSEQ * TLEN * G4 * sizeof(float);  // 196.6 MB
    if (ws_size >= need_f32) {
        float* xg = (float*)d_ws;
        xg_kernel<float><<<dim3(TLEN / 2, BATCH), 512, 0, stream>>>(x, W_ih, b_ih, b_hh, xg);
        lstm_kernel<float><<<NSEQ / 16, 512, 0, stream>>>(xg, W_hh, W_fc, b_fc, out);
    } else {
        _Float16* xg = (_Float16*)d_ws;
        xg_kernel<_Float16><<<dim3(TLEN / 2, BATCH), 512, 0, stream>>>(x, W_ih, b_ih, b_hh, xg);
        lstm_kernel<_Float16><<<NSEQ / 16, 512, 0, stream>>>(xg, W_hh, W_fc, b_fc, out);
    }
}